// Round 13
// baseline (227.123 us; speedup 1.0000x reference)
//
#include <hip/hip_runtime.h>
#include <hip/hip_bf16.h>
#include <math.h>

#define HIDDEN 1024
#define ADIM 32
#define NEMB 32
#define BB 128
#define TT 16
#define NROWS (BB*TT)   // 2048
#define KSPLIT 2

// LDS B layout (BN=512, BK=32): [gn:32][oct:4][(n&15) x 8 u16 + koff]
#define OCT_STRIDE 136                  // u16: 128 data + 8 pad
#define GN_STRIDE  552                  // u16: 4*136 + 8 pad
#define BS_U16     (32 * GN_STRIDE)     // 17664 u16 = 35328 B per buffer

typedef float f32x4 __attribute__((ext_vector_type(4)));
typedef short bf16x8 __attribute__((ext_vector_type(8)));
typedef unsigned short u16;

static __device__ __forceinline__ u16 f2bf(float f) {
    union { __hip_bfloat16 h; u16 u; } cv;
    cv.h = __float2bfloat16(f);   // RNE
    return cv.u;
}

// raw barrier: completes LDS ops, leaves global loads in flight (no vmcnt drain)
#define BARRIER() do { \
    asm volatile("s_waitcnt lgkmcnt(0)" ::: "memory"); \
    __builtin_amdgcn_s_barrier(); \
    asm volatile("" ::: "memory"); \
} while (0)

// ws layout:
//  [0, 4096)   : meta ints: [0..31]=cnt, [32..63]=off, [64..191]=blist,
//                [192]=ntiles, [200+4i..]=tiles (row0, rows, e)
//  xg  @ 4096  : 2048 x 2048 bf16 (8MB), grouped rows
//  yg  @ +8MB  : 2048 x 1024 bf16 (4MB), grouped rows
//  pbuf @ +4MB : KSPLIT x 2048 x 1024 f32 (16MB)

__global__ void prep_kernel(const int* __restrict__ cat, int* __restrict__ meta) {
    __shared__ int c[BB];
    int tid = threadIdx.x;
    if (tid < BB) c[tid] = cat[tid];
    __syncthreads();
    if (tid == 0) {
        int cnt[NEMB];
        for (int e = 0; e < NEMB; e++) cnt[e] = 0;
        for (int b = 0; b < BB; b++) cnt[c[b]]++;
        int off = 0;
        for (int e = 0; e < NEMB; e++) { meta[e] = cnt[e]; meta[32 + e] = off; off += cnt[e]; }
        int pos[NEMB];
        for (int e = 0; e < NEMB; e++) pos[e] = meta[32 + e];
        for (int b = 0; b < BB; b++) { int e = c[b]; meta[64 + pos[e]] = b; pos[e]++; }
        int nt = 0;
        for (int e = 0; e < NEMB; e++) {
            int Me = cnt[e] * TT;
            int base = meta[32 + e] * TT;
            for (int mb = 0; mb * 64 < Me; mb++) {
                int rows = Me - mb * 64; if (rows > 64) rows = 64;
                meta[200 + 4 * nt + 0] = base + mb * 64;
                meta[200 + 4 * nt + 1] = rows;
                meta[200 + 4 * nt + 2] = e;
                nt++;
            }
        }
        meta[192] = nt;   // <= 56
    }
}

// Layer 1 + PE, written grouped as bf16.
__global__ __launch_bounds__(256) void build_x_kernel(
    const float* __restrict__ actions, const int* __restrict__ timesteps,
    const int* __restrict__ cat_ids, const float* __restrict__ W1,
    const float* __restrict__ b1, const int* __restrict__ meta,
    u16* __restrict__ xg)
{
    int sb = blockIdx.x;
    int b  = meta[64 + sb];
    int e  = cat_ids[b];
    int tid = threadIdx.x;

    __shared__ float act[TT][ADIM];
    for (int i = tid; i < TT * ADIM; i += 256)
        act[i / ADIM][i % ADIM] = actions[(size_t)b * TT * ADIM + i];
    __syncthreads();

    float tau = (float)timesteps[b];

    for (int h = tid; h < HIDDEN; h += 256) {
        float acc[TT];
        #pragma unroll
        for (int t = 0; t < TT; t++) acc[t] = 0.f;
        for (int d = 0; d < ADIM; d++) {
            float w = W1[((size_t)e * ADIM + d) * HIDDEN + h];
            #pragma unroll
            for (int t = 0; t < TT; t++) acc[t] += act[t][d] * w;
        }
        float bv = b1[(size_t)e * HIDDEN + h];
        for (int t = 0; t < TT; t++)
            xg[(size_t)(sb * TT + t) * 2048 + h] = f2bf(acc[t] + bv);
    }

    for (int j = tid; j < HIDDEN; j += 256) {
        int i = j >> 1;
        float arg = tau * expf((float)i * -0.017988946f);
        float v = (j & 1) ? cosf(arg) : sinf(arg);
        u16 bv = f2bf(v);
        for (int t = 0; t < TT; t++)
            xg[(size_t)(sb * TT + t) * 2048 + 1024 + j] = bv;
    }
}

// Streaming grouped GEMM, split-K=2 partials, 2KB-contiguous row visits.
// 1D grid: bid = kc(2) + 2*nq(2) + 4*slot -> 224 blocks (single occupancy
// round). Block: 1024 thr (16 waves, 2m x 8n), tile 64m x 512n, BK=32,
// dbuf LDS (70.6KB). Per staging instruction each wave reads 1KB linear;
// a block covers a 2KB half of every 4KB W row; the sibling nq block
// (adjacent bid, co-scheduled) covers the other half. r11 pipeline:
// counted-vmcnt WRITEB, A reg-dbuf one step ahead, clamped unconditional
// prefetch (static vmcnt counts), raw lgkm-only barriers.
__global__ __launch_bounds__(1024, 1) void gemm_stream(
    const u16* __restrict__ X,        // grouped rows bf16, ld = ldx
    const float* __restrict__ W,      // (NEMB, Kdim, 1024) f32
    float* __restrict__ pbuf,         // KSPLIT x 2048 x 1024 f32
    const int* __restrict__ meta,
    int Kdim, int ldx)
{
    int bid  = blockIdx.x;
    int kc   = bid & 1;
    int nq   = (bid >> 1) & 1;
    int slot = bid >> 2;
    if (slot >= meta[192]) return;
    int row0      = meta[200 + 4 * slot + 0];
    int rowsValid = meta[200 + 4 * slot + 1];
    int e         = meta[200 + 4 * slot + 2];

    int n0  = nq * 512;
    int KC  = Kdim / KSPLIT;
    int kc0 = kc * KC;
    int nT  = KC >> 5;          // K-steps of 32 (32 for K=2048, 16 for K=1024; even)
    int nTm1 = nT - 1;

    __shared__ u16 Bs[2][BS_U16];   // 70656 B

    int tid  = threadIdx.x;
    int lane = tid & 63;
    int wid  = tid >> 6;
    int wm   = wid & 1;     // m-half (32 rows)
    int wn   = wid >> 1;    // n-slice (64 cols = 4 gn), 0..7
    int l15  = lane & 15;
    int kh   = lane >> 4;   // k-octet of the wave's fragment (0..3)

    const float* Wp = W + (size_t)e * Kdim * 1024 + n0;

    // B stage map: bn4 = n-quad (0..127), bo = row-quad group (0..7);
    // per thread 4 rows (bo*4+r) x f32x4 -> per wave-instr 1KB linear.
    int bn4 = tid & 127;
    int bo  = tid >> 7;

    // A row indices (clamped to buffer bounds)
    int am[2];
    #pragma unroll
    for (int mi = 0; mi < 2; mi++) {
        int m = row0 + wm * 32 + mi * 16 + l15;
        if (m > NROWS - 1) m = NROWS - 1;
        am[mi] = m;
    }

    f32x4  bReg[4];             // 1-deep B stage (16 VGPR)
    bf16x8 a0[2], a1[2];        // A frags [mi], double-buffered (16 VGPR)

    f32x4 acc[2][4];
    #pragma unroll
    for (int mi = 0; mi < 2; mi++)
        #pragma unroll
        for (int g = 0; g < 4; g++)
            acc[mi][g] = (f32x4){0.f, 0.f, 0.f, 0.f};

    #define LOADB(kt) do { \
        int _kt = (kt) > nTm1 ? nTm1 : (kt); \
        int kb = kc0 + _kt * 32 + bo * 4; \
        _Pragma("unroll") \
        for (int r = 0; r < 4; r++) \
            bReg[r] = *(const f32x4*)&Wp[(size_t)(kb + r) * 1024 + bn4 * 4]; \
    } while (0)

    #define LOADA(reg, kt) do { \
        int _kt = (kt) > nTm1 ? nTm1 : (kt); \
        _Pragma("unroll") \
        for (int mi = 0; mi < 2; mi++) \
            reg[mi] = *(const bf16x8*)&X[(size_t)am[mi] * ldx + kc0 + _kt * 32 + kh * 8]; \
    } while (0)

    // LDS idx(u16) for (n,k): (n>>4)*552 + (k>>3)*136 + (n&15)*8 + (k&7).
    // For fixed bo, r=0..3 -> k=bo*4+r all in octet bo>>1, koff=(bo&1)*4+r.
    #define WRITEB(c) do { \
        _Pragma("unroll") \
        for (int j = 0; j < 4; j++) { \
            int n = bn4 * 4 + j; \
            ushort4 w = make_ushort4(f2bf(bReg[0][j]), f2bf(bReg[1][j]), \
                                     f2bf(bReg[2][j]), f2bf(bReg[3][j])); \
            *(ushort4*)&Bs[c][(n >> 4) * GN_STRIDE + (bo >> 1) * OCT_STRIDE \
                              + (n & 15) * 8 + (bo & 1) * 4] = w; \
        } \
    } while (0)

    #define COMPUTE(c, aP) do { \
        _Pragma("unroll") \
        for (int g = 0; g < 4; g++) { \
            int gn = wn * 4 + g; \
            bf16x8 bf = *(const bf16x8*)&Bs[c][gn * GN_STRIDE + kh * OCT_STRIDE + l15 * 8]; \
            _Pragma("unroll") \
            for (int mi = 0; mi < 2; mi++) \
                acc[mi][g] = __builtin_amdgcn_mfma_f32_16x16x32_bf16(aP[mi], bf, acc[mi][g], 0, 0, 0); \
        } \
    } while (0)

    // prologue FIFO: b(0) [4 ops], a0(0) [2], a1(1) [2]
    LOADB(0);
    LOADA(a0, 0);
    LOADA(a1, 1);

    for (int kt = 0; kt < nT; kt += 2) {
        WRITEB(0);                 // waits b(kt) only (counted vmcnt)
        LOADB(kt + 1);
        BARRIER();
        COMPUTE(0, a0);
        LOADA(a0, kt + 2);
        WRITEB(1);                 // waits b(kt+1)
        LOADB(kt + 2);
        BARRIER();
        COMPUTE(1, a1);
        LOADA(a1, kt + 3);
    }

    #undef LOADB
    #undef LOADA
    #undef WRITEB
    #undef COMPUTE

    // partial store (row-major pbuf), non-temporal (single-use)
    float* pb = pbuf + (size_t)kc * NROWS * 1024;
    int col = n0 + wn * 64 + l15;
    #pragma unroll
    for (int mi = 0; mi < 2; mi++) {
        #pragma unroll
        for (int r = 0; r < 4; r++) {
            int m = wm * 32 + mi * 16 + kh * 4 + r;
            if (m < rowsValid) {
                float* dst = pb + (size_t)(row0 + m) * 1024 + col;
                #pragma unroll
                for (int g = 0; g < 4; g++)
                    __builtin_nontemporal_store(acc[mi][g][r], &dst[g * 16]);
            }
        }
    }
}

// yg = bf16(swish(sum_kc pbuf + b2)), grouped rows
__global__ __launch_bounds__(256) void reduce_mid(
    const float* __restrict__ pbuf, const float* __restrict__ b2,
    const int* __restrict__ meta, const int* __restrict__ cat,
    u16* __restrict__ yg)
{
    int r = blockIdx.x;
    int e = cat[meta[64 + (r >> 4)]];
    int c = threadIdx.x * 4;
    f32x4 s = __builtin_nontemporal_load((const f32x4*)&pbuf[(size_t)r * 1024 + c]);
    #pragma unroll
    for (int kc = 1; kc < KSPLIT; kc++) {
        f32x4 t = __builtin_nontemporal_load(
            (const f32x4*)&pbuf[(size_t)kc * NROWS * 1024 + (size_t)r * 1024 + c]);
        s = s + t;
    }
    f32x4 bb = *(const f32x4*)&b2[(size_t)e * 1024 + c];
    ushort4 o;
    float h0 = s[0] + bb[0]; o.x = f2bf(h0 / (1.f + expf(-h0)));
    float h1 = s[1] + bb[1]; o.y = f2bf(h1 / (1.f + expf(-h1)));
    float h2 = s[2] + bb[2]; o.z = f2bf(h2 / (1.f + expf(-h2)));
    float h3 = s[3] + bb[3]; o.w = f2bf(h3 / (1.f + expf(-h3)));
    *(ushort4*)&yg[(size_t)r * 1024 + c] = o;
}

// out[natural] = sum_kc pbuf + b3
__global__ __launch_bounds__(256) void reduce_out(
    const float* __restrict__ pbuf, const float* __restrict__ b3,
    const int* __restrict__ meta, const int* __restrict__ cat,
    float* __restrict__ out)
{
    int r = blockIdx.x;
    int bnat = meta[64 + (r >> 4)];
    int e = cat[bnat];
    int c = threadIdx.x * 4;
    f32x4 s = __builtin_nontemporal_load((const f32x4*)&pbuf[(size_t)r * 1024 + c]);
    #pragma unroll
    for (int kc = 1; kc < KSPLIT; kc++) {
        f32x4 t = __builtin_nontemporal_load(
            (const f32x4*)&pbuf[(size_t)kc * NROWS * 1024 + (size_t)r * 1024 + c]);
        s = s + t;
    }
    f32x4 bb = *(const f32x4*)&b3[(size_t)e * 1024 + c];
    s = s + bb;
    __builtin_nontemporal_store(s, (f32x4*)&out[((size_t)bnat * TT + (r & 15)) * 1024 + c]);
}

extern "C" void kernel_launch(void* const* d_in, const int* in_sizes, int n_in,
                              void* d_out, int out_size, void* d_ws, size_t ws_size,
                              hipStream_t stream) {
    const float* actions   = (const float*)d_in[0];
    const int*   timesteps = (const int*)d_in[1];
    const int*   cat_ids   = (const int*)d_in[2];
    const float* W1        = (const float*)d_in[3];
    const float* b1        = (const float*)d_in[4];
    const float* W2        = (const float*)d_in[5];
    const float* b2        = (const float*)d_in[6];
    const float* W3        = (const float*)d_in[7];
    const float* b3        = (const float*)d_in[8];
    float* out = (float*)d_out;

    int*  meta  = (int*)d_ws;
    u16*  xg    = (u16*)((char*)d_ws + 4096);
    u16*  yg    = (u16*)((char*)d_ws + 4096 + 8ull * 1024 * 1024);
    float* pbuf = (float*)((char*)d_ws + 4096 + 12ull * 1024 * 1024);

    prep_kernel<<<1, 128, 0, stream>>>(cat_ids, meta);
    build_x_kernel<<<128, 256, 0, stream>>>(actions, timesteps, cat_ids, W1, b1, meta, xg);

    // layer 2: K=2048 (2 kc x 2 nq x <=56 slots = 224 blocks)
    gemm_stream<<<224, 1024, 0, stream>>>(xg, W2, pbuf, meta, 2048, 2048);
    reduce_mid<<<NROWS, 256, 0, stream>>>(pbuf, b2, meta, cat_ids, yg);

    // layer 3: K=1024
    gemm_stream<<<224, 1024, 0, stream>>>(yg, W3, pbuf, meta, 1024, 1024);
    reduce_out<<<NROWS, 256, 0, stream>>>(pbuf, b3, meta, cat_ids, out);
}

// Round 14
// 207.935 us; speedup vs baseline: 1.0923x; 1.0923x over previous
//
#include <hip/hip_runtime.h>
#include <hip/hip_bf16.h>
#include <math.h>

#define HIDDEN 1024
#define ADIM 32
#define NEMB 32
#define BB 128
#define TT 16
#define NROWS (BB*TT)   // 2048
#define KSPLIT 4

#define OCT_STRIDE 136    // u16: 128 data + 8 pad
#define GN_STRIDE  1096   // u16: 8*136 + 8 pad
#define BS_U16     (16 * GN_STRIDE)   // 17536 u16 = 35072 B per buffer

typedef float f32x4 __attribute__((ext_vector_type(4)));
typedef short bf16x8 __attribute__((ext_vector_type(8)));
typedef unsigned short u16;

static __device__ __forceinline__ u16 f2bf(float f) {
    union { __hip_bfloat16 h; u16 u; } cv;
    cv.h = __float2bfloat16(f);   // RNE
    return cv.u;
}

// raw barrier: completes LDS ops, leaves global loads in flight (no vmcnt drain)
#define BARRIER() do { \
    asm volatile("s_waitcnt lgkmcnt(0)" ::: "memory"); \
    __builtin_amdgcn_s_barrier(); \
    asm volatile("" ::: "memory"); \
} while (0)

// ws layout:
//  [0, 4096)   : meta ints: [0..31]=cnt, [32..63]=off, [64..191]=blist,
//                [192]=ntiles, [200+4i..]=tiles (row0, rows, e)
//  xg  @ 4096  : 2048 x 2048 bf16 (8MB), grouped rows
//  yg  @ +8MB  : 2048 x 1024 bf16 (4MB), grouped rows
//  pbuf @ +4MB : KSPLIT x 2048 x 1024 f32 (32MB)

__global__ void prep_kernel(const int* __restrict__ cat, int* __restrict__ meta) {
    __shared__ int c[BB];
    int tid = threadIdx.x;
    if (tid < BB) c[tid] = cat[tid];
    __syncthreads();
    if (tid == 0) {
        int cnt[NEMB];
        for (int e = 0; e < NEMB; e++) cnt[e] = 0;
        for (int b = 0; b < BB; b++) cnt[c[b]]++;
        int off = 0;
        for (int e = 0; e < NEMB; e++) { meta[e] = cnt[e]; meta[32 + e] = off; off += cnt[e]; }
        int pos[NEMB];
        for (int e = 0; e < NEMB; e++) pos[e] = meta[32 + e];
        for (int b = 0; b < BB; b++) { int e = c[b]; meta[64 + pos[e]] = b; pos[e]++; }
        int nt = 0;
        for (int e = 0; e < NEMB; e++) {
            int Me = cnt[e] * TT;
            int base = meta[32 + e] * TT;
            for (int mb = 0; mb * 64 < Me; mb++) {
                int rows = Me - mb * 64; if (rows > 64) rows = 64;
                meta[200 + 4 * nt + 0] = base + mb * 64;
                meta[200 + 4 * nt + 1] = rows;
                meta[200 + 4 * nt + 2] = e;
                nt++;
            }
        }
        meta[192] = nt;   // <= 56
    }
}

// Layer 1 + PE, written grouped as bf16.
__global__ __launch_bounds__(256) void build_x_kernel(
    const float* __restrict__ actions, const int* __restrict__ timesteps,
    const int* __restrict__ cat_ids, const float* __restrict__ W1,
    const float* __restrict__ b1, const int* __restrict__ meta,
    u16* __restrict__ xg)
{
    int sb = blockIdx.x;
    int b  = meta[64 + sb];
    int e  = cat_ids[b];
    int tid = threadIdx.x;

    __shared__ float act[TT][ADIM];
    for (int i = tid; i < TT * ADIM; i += 256)
        act[i / ADIM][i % ADIM] = actions[(size_t)b * TT * ADIM + i];
    __syncthreads();

    float tau = (float)timesteps[b];

    for (int h = tid; h < HIDDEN; h += 256) {
        float acc[TT];
        #pragma unroll
        for (int t = 0; t < TT; t++) acc[t] = 0.f;
        for (int d = 0; d < ADIM; d++) {
            float w = W1[((size_t)e * ADIM + d) * HIDDEN + h];
            #pragma unroll
            for (int t = 0; t < TT; t++) acc[t] += act[t][d] * w;
        }
        float bv = b1[(size_t)e * HIDDEN + h];
        for (int t = 0; t < TT; t++)
            xg[(size_t)(sb * TT + t) * 2048 + h] = f2bf(acc[t] + bv);
    }

    for (int j = tid; j < HIDDEN; j += 256) {
        int i = j >> 1;
        float arg = tau * expf((float)i * -0.017988946f);
        float v = (j & 1) ? cosf(arg) : sinf(arg);
        u16 bv = f2bf(v);
        for (int t = 0; t < TT; t++)
            xg[(size_t)(sb * TT + t) * 2048 + 1024 + j] = bv;
    }
}

// Streaming grouped GEMM, split-K partials (best-known r11 configuration):
// 1D grid: bid = kc + 4*nq + 16*slot. Tile 64m x 256n, BK=64, dbuf LDS,
// 1-deep B reg prefetch (counted-vmcnt WRITEB), A double-buffered in regs
// one K-step ahead (refilled AFTER its consuming COMPUTE), unconditional
// clamped prefetch -> static vmcnt counts, raw lgkm-only barriers.
__global__ __launch_bounds__(512, 4) void gemm_stream(
    const u16* __restrict__ X,        // grouped rows bf16, ld = ldx
    const float* __restrict__ W,      // (NEMB, Kdim, 1024) f32
    float* __restrict__ pbuf,         // KSPLIT x 2048 x 1024 f32
    const int* __restrict__ meta,
    int Kdim, int ldx)
{
    int bid  = blockIdx.x;
    int kc   = bid & 3;
    int nq   = (bid >> 2) & 3;
    int slot = bid >> 4;
    if (slot >= meta[192]) return;
    int row0      = meta[200 + 4 * slot + 0];
    int rowsValid = meta[200 + 4 * slot + 1];
    int e         = meta[200 + 4 * slot + 2];

    int n0  = nq * 256;
    int KC  = Kdim / KSPLIT;
    int kc0 = kc * KC;
    int nT  = KC >> 6;          // K-steps of 64 (8 for K=2048, 4 for K=1024; even)
    int nTm1 = nT - 1;

    __shared__ u16 Bs[2][BS_U16];

    int tid  = threadIdx.x;
    int lane = tid & 63;
    int wid  = tid >> 6;
    int wm   = wid & 1;     // m-half (32 rows)
    int wn   = wid >> 1;    // n-quarter (64 cols = 4 gn)

    const float* Wp = W + (size_t)e * Kdim * 1024 + n0;

    // B stage map: bn4 = n-quad (0..63), bo = k-octet (0..7); 8 rows f32x4 each.
    int bn4 = tid & 63;
    int bo  = tid >> 6;

    // A row indices (clamped to buffer bounds)
    int am[2];
    #pragma unroll
    for (int mi = 0; mi < 2; mi++) {
        int m = row0 + wm * 32 + mi * 16 + (lane & 15);
        if (m > NROWS - 1) m = NROWS - 1;
        am[mi] = m;
    }

    f32x4  bReg[8];             // 1-deep B stage (32 VGPR)
    bf16x8 a0[4], a1[4];        // A frags [h*2+mi], double-buffered (32 VGPR)

    f32x4 acc[2][4];
    #pragma unroll
    for (int mi = 0; mi < 2; mi++)
        #pragma unroll
        for (int g = 0; g < 4; g++)
            acc[mi][g] = (f32x4){0.f, 0.f, 0.f, 0.f};

    #define LOADB(kt) do { \
        int _kt = (kt) > nTm1 ? nTm1 : (kt); \
        int kb = kc0 + _kt * 64 + bo * 8; \
        _Pragma("unroll") \
        for (int r = 0; r < 8; r++) \
            bReg[r] = *(const f32x4*)&Wp[(size_t)(kb + r) * 1024 + bn4 * 4]; \
    } while (0)

    #define LOADA(reg, kt) do { \
        int _kt = (kt) > nTm1 ? nTm1 : (kt); \
        _Pragma("unroll") \
        for (int h = 0; h < 2; h++) \
            _Pragma("unroll") \
            for (int mi = 0; mi < 2; mi++) \
                reg[h * 2 + mi] = *(const bf16x8*)&X[(size_t)am[mi] * ldx + kc0 + _kt * 64 + h * 32 + (lane >> 4) * 8]; \
    } while (0)

    #define WRITEB(c) do { \
        _Pragma("unroll") \
        for (int j = 0; j < 4; j++) { \
            int n = bn4 * 4 + j; \
            bf16x8 v; \
            _Pragma("unroll") \
            for (int r = 0; r < 8; r++) v[r] = (short)f2bf(bReg[r][j]); \
            *(bf16x8*)&Bs[c][(n >> 4) * GN_STRIDE + bo * OCT_STRIDE + (n & 15) * 8] = v; \
        } \
    } while (0)

    #define COMPUTE(c, aP) do { \
        _Pragma("unroll") \
        for (int h = 0; h < 2; h++) { \
            _Pragma("unroll") \
            for (int g = 0; g < 4; g++) { \
                int gn = wn * 4 + g; \
                bf16x8 bf = *(const bf16x8*)&Bs[c][gn * GN_STRIDE + (h * 4 + (lane >> 4)) * OCT_STRIDE + (lane & 15) * 8]; \
                _Pragma("unroll") \
                for (int mi = 0; mi < 2; mi++) \
                    acc[mi][g] = __builtin_amdgcn_mfma_f32_16x16x32_bf16(aP[h * 2 + mi], bf, acc[mi][g], 0, 0, 0); \
            } \
        } \
    } while (0)

    // prologue FIFO: b(0), a0(0), a1(1)
    LOADB(0);
    LOADA(a0, 0);
    LOADA(a1, 1);

    for (int kt = 0; kt < nT; kt += 2) {
        WRITEB(0);                 // waits b(kt) only
        LOADB(kt + 1);
        BARRIER();
        COMPUTE(0, a0);
        LOADA(a0, kt + 2);
        WRITEB(1);                 // waits b(kt+1)
        LOADB(kt + 2);
        BARRIER();
        COMPUTE(1, a1);
        LOADA(a1, kt + 3);
    }

    #undef LOADB
    #undef LOADA
    #undef WRITEB
    #undef COMPUTE

    // partial store (row-major pbuf)
    float* pb = pbuf + (size_t)kc * NROWS * 1024;
    int col = n0 + wn * 64 + (lane & 15);
    #pragma unroll
    for (int mi = 0; mi < 2; mi++) {
        #pragma unroll
        for (int r = 0; r < 4; r++) {
            int m = wm * 32 + mi * 16 + ((lane >> 4) << 2) + r;
            if (m < rowsValid) {
                float* dst = pb + (size_t)(row0 + m) * 1024 + col;
                #pragma unroll
                for (int g = 0; g < 4; g++)
                    dst[g * 16] = acc[mi][g][r];
            }
        }
    }
}

// yg = bf16(swish(sum_kc pbuf + b2)), grouped rows
__global__ __launch_bounds__(256) void reduce_mid(
    const float* __restrict__ pbuf, const float* __restrict__ b2,
    const int* __restrict__ meta, const int* __restrict__ cat,
    u16* __restrict__ yg)
{
    int r = blockIdx.x;
    int e = cat[meta[64 + (r >> 4)]];
    int c = threadIdx.x * 4;
    f32x4 s = *(const f32x4*)&pbuf[(size_t)r * 1024 + c];
    #pragma unroll
    for (int kc = 1; kc < KSPLIT; kc++) {
        f32x4 t = *(const f32x4*)&pbuf[(size_t)kc * NROWS * 1024 + (size_t)r * 1024 + c];
        s = s + t;
    }
    f32x4 bb = *(const f32x4*)&b2[(size_t)e * 1024 + c];
    ushort4 o;
    float h0 = s[0] + bb[0]; o.x = f2bf(h0 / (1.f + expf(-h0)));
    float h1 = s[1] + bb[1]; o.y = f2bf(h1 / (1.f + expf(-h1)));
    float h2 = s[2] + bb[2]; o.z = f2bf(h2 / (1.f + expf(-h2)));
    float h3 = s[3] + bb[3]; o.w = f2bf(h3 / (1.f + expf(-h3)));
    *(ushort4*)&yg[(size_t)r * 1024 + c] = o;
}

// out[natural] = sum_kc pbuf + b3
__global__ __launch_bounds__(256) void reduce_out(
    const float* __restrict__ pbuf, const float* __restrict__ b3,
    const int* __restrict__ meta, const int* __restrict__ cat,
    float* __restrict__ out)
{
    int r = blockIdx.x;
    int bnat = meta[64 + (r >> 4)];
    int e = cat[bnat];
    int c = threadIdx.x * 4;
    f32x4 s = *(const f32x4*)&pbuf[(size_t)r * 1024 + c];
    #pragma unroll
    for (int kc = 1; kc < KSPLIT; kc++) {
        f32x4 t = *(const f32x4*)&pbuf[(size_t)kc * NROWS * 1024 + (size_t)r * 1024 + c];
        s = s + t;
    }
    f32x4 bb = *(const f32x4*)&b3[(size_t)e * 1024 + c];
    s = s + bb;
    *(f32x4*)&out[((size_t)bnat * TT + (r & 15)) * 1024 + c] = s;
}

extern "C" void kernel_launch(void* const* d_in, const int* in_sizes, int n_in,
                              void* d_out, int out_size, void* d_ws, size_t ws_size,
                              hipStream_t stream) {
    const float* actions   = (const float*)d_in[0];
    const int*   timesteps = (const int*)d_in[1];
    const int*   cat_ids   = (const int*)d_in[2];
    const float* W1        = (const float*)d_in[3];
    const float* b1        = (const float*)d_in[4];
    const float* W2        = (const float*)d_in[5];
    const float* b2        = (const float*)d_in[6];
    const float* W3        = (const float*)d_in[7];
    const float* b3        = (const float*)d_in[8];
    float* out = (float*)d_out;

    int*  meta  = (int*)d_ws;
    u16*  xg    = (u16*)((char*)d_ws + 4096);
    u16*  yg    = (u16*)((char*)d_ws + 4096 + 8ull * 1024 * 1024);
    float* pbuf = (float*)((char*)d_ws + 4096 + 12ull * 1024 * 1024);

    prep_kernel<<<1, 128, 0, stream>>>(cat_ids, meta);
    build_x_kernel<<<128, 256, 0, stream>>>(actions, timesteps, cat_ids, W1, b1, meta, xg);

    // layer 2: K=2048
    gemm_stream<<<1024, 512, 0, stream>>>(xg, W2, pbuf, meta, 2048, 2048);
    reduce_mid<<<NROWS, 256, 0, stream>>>(pbuf, b2, meta, cat_ids, yg);

    // layer 3: K=1024
    gemm_stream<<<1024, 512, 0, stream>>>(yg, W3, pbuf, meta, 1024, 1024);
    reduce_out<<<NROWS, 256, 0, stream>>>(pbuf, b3, meta, cat_ids, out);
}